// Round 4
// baseline (814.460 us; speedup 1.0000x reference)
//
#include <hip/hip_runtime.h>

#define B_ 2
#define S_ 2048
#define H_ 16
#define HD_ 128
#define QKVROW 6144   // 3*2048, row length of qkv activation
#define M_ 4096       // B_*S_

typedef float f32x4 __attribute__((ext_vector_type(4)));
typedef __bf16 bf16x8 __attribute__((ext_vector_type(8)));
typedef unsigned short ushortx8 __attribute__((ext_vector_type(8)));

__device__ __forceinline__ float bf2f(unsigned short u) {
  union { unsigned u; float f; } v;
  v.u = ((unsigned)u) << 16;
  return v.f;
}
__device__ __forceinline__ unsigned short f2bf(float f) {
  union { float f; unsigned u; } v;
  v.f = f;
  unsigned r = v.u + 0x7fffu + ((v.u >> 16) & 1u);
  return (unsigned short)(r >> 16);
}

// Decide whether the raw input buffers are fp32 or bf16 by inspecting the
// exponent field of the EVEN ushorts of x's first 64 dwords. For bf16 data
// those are genuine bf16 N(0,1) values (exponent ~[100,135], 0 hits); for
// fp32 data they are low mantissa bits (uniform -> ~50% hits).
__device__ __forceinline__ bool sniff_fp32(const unsigned* __restrict__ w) {
  int weird = 0;
#pragma unroll
  for (int i = 0; i < 64; ++i) {
    const unsigned e = (w[i] >> 7) & 0xFFu;
    weird += (e >= 0xC0u || e <= 0x40u) ? 1 : 0;
  }
  return __builtin_amdgcn_readfirstlane(weird) >= 8;
}

// 8 contiguous elements starting at element index e, as bf16 ushorts.
__device__ __forceinline__ ushortx8 load8(const void* p, size_t e, bool f32) {
  if (f32) {
    const float* f = (const float*)p + e;
    ushortx8 o;
#pragma unroll
    for (int t = 0; t < 8; ++t) o[t] = f2bf(f[t]);
    return o;
  }
  return *(const ushortx8*)((const unsigned short*)p + e);
}

// ---------------------------------------------------------------------------
// C[m,n] = sum_k A[m,k]*B[n,k] + bias[n]. A element (m,k) lives at element
// index m*ars + (k>>7)*ahs + (k&127)   (ars=K, ahs=128 -> plain row-major).
// a_dyn/b_dyn/bias_dyn/c_dyn: 1 -> dtype follows the sniffed input dtype,
// 0 -> always bf16. m97-class structure, classic reg->LDS staging.
// ---------------------------------------------------------------------------
__global__ __launch_bounds__(256) void gemm_bt_bias(
    const void* __restrict__ A, const void* __restrict__ Bm,
    const void* __restrict__ bias, void* __restrict__ C,
    int N, int K, int ars, int ahs,
    int a_dyn, int b_dyn, int bias_dyn, int c_dyn,
    const unsigned* __restrict__ xprobe) {
  const bool f32in = sniff_fp32(xprobe);
  const bool aF = a_dyn && f32in, bF = b_dyn && f32in;
  const bool biF = bias_dyn && f32in, cF = c_dyn && f32in;

  __shared__ unsigned short As[128 * 64];
  __shared__ unsigned short Bs[128 * 64];
  const int tid = threadIdx.x;
  const int lane = tid & 63, wave = tid >> 6;
  const int l15 = lane & 15, quad = lane >> 4;
  const int m0 = blockIdx.y * 128, n0 = blockIdx.x * 128;
  const int wr = (wave >> 1) * 64, wc = (wave & 1) * 64;

  f32x4 acc[4][4];
#pragma unroll
  for (int r = 0; r < 4; ++r)
#pragma unroll
    for (int c = 0; c < 4; ++c) acc[r][c] = (f32x4){0.f, 0.f, 0.f, 0.f};

  for (int k0 = 0; k0 < K; k0 += 64) {
    const int kh = (k0 >> 7) * ahs + (k0 & 127);  // head-strided k base for A
    // stage 128x64 A-tile and B-tile: 1024 16B-units each, 4 per thread
    ushortx8 ra[4], rb[4];
#pragma unroll
    for (int p = 0; p < 4; ++p) {
      const int u = p * 256 + tid;
      const int row = u >> 3, cu = u & 7;  // 8 units (128B) per LDS row
      ra[p] = load8(A, (size_t)(m0 + row) * ars + kh + cu * 8, aF);
      rb[p] = load8(Bm, (size_t)(n0 + row) * K + k0 + cu * 8, bF);
    }
    __syncthreads();  // prior iteration's frag reads complete on all waves
#pragma unroll
    for (int p = 0; p < 4; ++p) {
      const int u = p * 256 + tid;
      *(ushortx8*)&As[u * 8] = ra[p];
      *(ushortx8*)&Bs[u * 8] = rb[p];
    }
    __syncthreads();  // tiles visible to all waves
#pragma unroll
    for (int s = 0; s < 2; ++s) {
      bf16x8 af[4], bf[4];
#pragma unroll
      for (int r = 0; r < 4; ++r)
        af[r] = *(const bf16x8*)&As[(wr + r * 16 + l15) * 64 + (s * 4 + quad) * 8];
#pragma unroll
      for (int c = 0; c < 4; ++c)
        bf[c] = *(const bf16x8*)&Bs[(wc + c * 16 + l15) * 64 + (s * 4 + quad) * 8];
#pragma unroll
      for (int r = 0; r < 4; ++r)
#pragma unroll
        for (int c = 0; c < 4; ++c)
          acc[r][c] = __builtin_amdgcn_mfma_f32_16x16x32_bf16(af[r], bf[c], acc[r][c], 0, 0, 0);
    }
  }

#pragma unroll
  for (int c = 0; c < 4; ++c) {
    const int col = n0 + wc + c * 16 + l15;
    const float bv = biF ? ((const float*)bias)[col]
                         : bf2f(((const unsigned short*)bias)[col]);
#pragma unroll
    for (int r = 0; r < 4; ++r) {
      const int row = m0 + wr + r * 16 + quad * 4;
#pragma unroll
      for (int i = 0; i < 4; ++i) {
        const float v = acc[r][c][i] + bv;
        const size_t idx = (size_t)(row + i) * N + col;
        if (cF) ((float*)C)[idx] = v;
        else    ((unsigned short*)C)[idx] = f2bf(v);
      }
    }
  }
}

// ---------------------------------------------------------------------------
// In-place deinterleave+RoPE on the q,k slots of qkv [b,s,h,3,hd] (q also
// pre-scaled by hd^-0.5), plus Vt [b,h,hd,s] built from the v slot.
// All bf16 workspace; dtype-independent of the raw inputs.
// ---------------------------------------------------------------------------
__global__ __launch_bounds__(256) void rope_vt(
    unsigned short* qkv, unsigned short* __restrict__ Vt) {
  __shared__ unsigned short vs[64 * 136];
  const int b = blockIdx.z, h = blockIdx.y, s0 = blockIdx.x * 64;
  const int tid = threadIdx.x;
  const int r = tid >> 2, cpart = (tid & 3) * 32;  // row in tile, 32-elem slice
  const int s = s0 + r;
  unsigned short* base = qkv + (size_t)(b * S_ + s) * QKVROW + h * 384;
  const int j0 = cpart >> 1;

  // Load everything this thread needs BEFORE any in-place write.
  ushortx8 ivq[4], ivk[4], ivv[4];
#pragma unroll
  for (int i = 0; i < 4; ++i) {
    ivq[i] = *(const ushortx8*)&base[cpart + i * 8];
    ivk[i] = *(const ushortx8*)&base[128 + cpart + i * 8];
    ivv[i] = *(const ushortx8*)&base[256 + cpart + i * 8];
  }

  float cs[16], sn[16];
#pragma unroll
  for (int t = 0; t < 16; ++t) {
    const float invf = expf(-(float)(j0 + t) * 0.14391156831212787f);  // ln(1e4)/64
    sincosf((float)s * invf, &sn[t], &cs[t]);
  }

  __syncthreads();  // all reads of q/k rows done before anyone writes them

#pragma unroll
  for (int which = 0; which < 2; ++which) {
    const ushortx8* iv = (which == 0) ? ivq : ivk;
    const float scale = (which == 0) ? 0.08838834764831845f : 1.0f;  // hd^-0.5
    ushortx8 o1a, o1b, o2a, o2b;
#pragma unroll
    for (int t = 0; t < 16; ++t) {
      const float x1 = bf2f(iv[(2 * t) >> 3][(2 * t) & 7]);          // orig[2j]
      const float x2 = bf2f(iv[(2 * t + 1) >> 3][(2 * t + 1) & 7]);  // orig[2j+1]
      const unsigned short r1 = f2bf((x1 * cs[t] - x2 * sn[t]) * scale);
      const unsigned short r2 = f2bf((x2 * cs[t] + x1 * sn[t]) * scale);
      if (t < 8) { o1a[t] = r1; o2a[t] = r2; }
      else       { o1b[t - 8] = r1; o2b[t - 8] = r2; }
    }
    unsigned short* out = base + which * 128;
    *(ushortx8*)&out[j0] = o1a;
    *(ushortx8*)&out[j0 + 8] = o1b;
    *(ushortx8*)&out[64 + j0] = o2a;
    *(ushortx8*)&out[64 + j0 + 8] = o2b;
  }

  // V transpose through LDS -> Vt[b,h,hd,s]
#pragma unroll
  for (int i = 0; i < 4; ++i)
    *(ushortx8*)&vs[r * 136 + cpart + i * 8] = ivv[i];
  __syncthreads();
  const size_t vtb = (size_t)(b * H_ + h) * HD_ * S_ + s0;
#pragma unroll
  for (int it = 0; it < 4; ++it) {
    const int a = tid + it * 256;
    const int d = a >> 3, sc = (a & 7) * 8;
    ushortx8 o;
#pragma unroll
    for (int t = 0; t < 8; ++t) o[t] = vs[(sc + t) * 136 + d];
    *(ushortx8*)&Vt[vtb + (size_t)d * S_ + sc] = o;
  }
}

// ---------------------------------------------------------------------------
// Flash attention, causal. grid (S/128, B*H), 256 threads (4 waves).
// Q/K from qkv's rope'd slots (bf16 ws); V from Vt. ctx written into the
// consumed, block-private q slot. Dtype-independent of raw inputs.
// ---------------------------------------------------------------------------
__global__ __launch_bounds__(256) void attn(
    unsigned short* qkv, const unsigned short* __restrict__ Vt) {
  __shared__ unsigned short Ks[128 * 128];  // 32KB (P overlays here later)
  __shared__ unsigned short Vs[128 * 128];  // 32KB
  const int qt = blockIdx.x, bh = blockIdx.y;
  const int b = bh >> 4, h = bh & 15;
  const int tid = threadIdx.x, lane = tid & 63, wave = tid >> 6;
  const int l15 = lane & 15, quad = lane >> 4;

  unsigned short* qh = qkv + (size_t)b * S_ * QKVROW + h * 384;
  const unsigned short* Vb = Vt + (size_t)bh * HD_ * S_;

  bf16x8 aq[2][4];
#pragma unroll
  for (int rt = 0; rt < 2; ++rt)
#pragma unroll
    for (int ks = 0; ks < 4; ++ks)
      aq[rt][ks] = *(const bf16x8*)&qh[(size_t)(qt * 128 + wave * 32 + rt * 16 + l15) * QKVROW +
                                       ks * 32 + quad * 8];

  f32x4 o[2][8];
  float mrow[2][4], lrow[2][4];
#pragma unroll
  for (int rt = 0; rt < 2; ++rt) {
#pragma unroll
    for (int ct = 0; ct < 8; ++ct) o[rt][ct] = (f32x4){0.f, 0.f, 0.f, 0.f};
#pragma unroll
    for (int i = 0; i < 4; ++i) { mrow[rt][i] = -1e30f; lrow[rt][i] = 0.f; }
  }

  for (int j = 0; j <= qt; ++j) {
    ushortx8 rk[8], rv[8];
#pragma unroll
    for (int p = 0; p < 8; ++p) {
      const int u = p * 256 + tid;
      const int row = u >> 4, cu = u & 15;  // 16 units (256B) per LDS row
      rk[p] = *(const ushortx8*)(qh + (size_t)(j * 128 + row) * QKVROW + 128 + cu * 8);
      rv[p] = *(const ushortx8*)(Vb + (size_t)row * S_ + j * 128 + cu * 8);
    }
    __syncthreads();  // prior iteration's P/V reads complete on all waves
#pragma unroll
    for (int p = 0; p < 8; ++p) {
      const int u = p * 256 + tid;
      *(ushortx8*)&Ks[u * 8] = rk[p];
      *(ushortx8*)&Vs[u * 8] = rv[p];
    }
    __syncthreads();

    // S = Q K^T (Q pre-scaled)
    f32x4 sacc[2][8];
#pragma unroll
    for (int rt = 0; rt < 2; ++rt)
#pragma unroll
      for (int ct = 0; ct < 8; ++ct) sacc[rt][ct] = (f32x4){0.f, 0.f, 0.f, 0.f};
#pragma unroll
    for (int ks = 0; ks < 4; ++ks) {
      bf16x8 bk[8];
#pragma unroll
      for (int ct = 0; ct < 8; ++ct)
        bk[ct] = *(const bf16x8*)&Ks[(ct * 16 + l15) * 128 + (ks * 4 + quad) * 8];
#pragma unroll
      for (int rt = 0; rt < 2; ++rt)
#pragma unroll
        for (int ct = 0; ct < 8; ++ct)
          sacc[rt][ct] = __builtin_amdgcn_mfma_f32_16x16x32_bf16(aq[rt][ks], bk[ct], sacc[rt][ct], 0, 0, 0);
    }

    if (j == qt) {  // causal mask on diagonal tile
#pragma unroll
      for (int rt = 0; rt < 2; ++rt)
#pragma unroll
        for (int ct = 0; ct < 8; ++ct)
#pragma unroll
          for (int i = 0; i < 4; ++i) {
            const int row = wave * 32 + rt * 16 + quad * 4 + i;
            const int col = ct * 16 + l15;
            if (col > row) sacc[rt][ct][i] = -1e30f;
          }
    }

    // online softmax (C-layout rows = quad*4+i; reduce over 16 lanes of quad)
    float alpha[2][4];
#pragma unroll
    for (int rt = 0; rt < 2; ++rt)
#pragma unroll
      for (int i = 0; i < 4; ++i) {
        float m = sacc[rt][0][i];
#pragma unroll
        for (int ct = 1; ct < 8; ++ct) m = fmaxf(m, sacc[rt][ct][i]);
#pragma unroll
        for (int off = 1; off < 16; off <<= 1) m = fmaxf(m, __shfl_xor(m, off));
        const float mn = fmaxf(mrow[rt][i], m);
        alpha[rt][i] = __expf(mrow[rt][i] - mn);
        mrow[rt][i] = mn;
        float rsum = 0.f;
#pragma unroll
        for (int ct = 0; ct < 8; ++ct) {
          const float p = __expf(sacc[rt][ct][i] - mn);
          sacc[rt][ct][i] = p;
          rsum += p;
        }
#pragma unroll
        for (int off = 1; off < 16; off <<= 1) rsum += __shfl_xor(rsum, off);
        lrow[rt][i] = lrow[rt][i] * alpha[rt][i] + rsum;
#pragma unroll
        for (int ct = 0; ct < 8; ++ct) o[rt][ct][i] *= alpha[rt][i];
      }

    __syncthreads();  // all waves done reading Ks; safe to overlay P
    unsigned short* Ps = &Ks[wave * 4096];  // 32x128 per wave, linear
#pragma unroll
    for (int rt = 0; rt < 2; ++rt)
#pragma unroll
      for (int ct = 0; ct < 8; ++ct)
#pragma unroll
        for (int i = 0; i < 4; ++i)
          Ps[(rt * 16 + quad * 4 + i) * 128 + ct * 16 + l15] = f2bf(sacc[rt][ct][i]);

    // O += P * V
#pragma unroll
    for (int ks = 0; ks < 4; ++ks) {
      bf16x8 ap[2];
#pragma unroll
      for (int rt = 0; rt < 2; ++rt)
        ap[rt] = *(const bf16x8*)&Ps[(rt * 16 + l15) * 128 + (ks * 4 + quad) * 8];
      bf16x8 bv[8];
#pragma unroll
      for (int ct = 0; ct < 8; ++ct)
        bv[ct] = *(const bf16x8*)&Vs[(ct * 16 + l15) * 128 + (ks * 4 + quad) * 8];
#pragma unroll
      for (int rt = 0; rt < 2; ++rt)
#pragma unroll
        for (int ct = 0; ct < 8; ++ct)
          o[rt][ct] = __builtin_amdgcn_mfma_f32_16x16x32_bf16(ap[rt], bv[ct], o[rt][ct], 0, 0, 0);
    }
  }

  __syncthreads();

  // write ctx into the (consumed) q slot
#pragma unroll
  for (int rt = 0; rt < 2; ++rt) {
    float inv[4];
#pragma unroll
    for (int i = 0; i < 4; ++i) inv[i] = 1.0f / lrow[rt][i];
#pragma unroll
    for (int ct = 0; ct < 8; ++ct)
#pragma unroll
      for (int i = 0; i < 4; ++i) {
        const int srow = qt * 128 + wave * 32 + rt * 16 + quad * 4 + i;
        qh[(size_t)srow * QKVROW + ct * 16 + l15] = f2bf(o[rt][ct][i] * inv[i]);
      }
  }
}

// Diagnostic: if ws_size is too small, fill out with bf16 1024.0 sentinel.
__global__ void ws_sentinel(unsigned short* out, int n) {
  const int i = blockIdx.x * 256 + threadIdx.x;
  if (i < n) out[i] = 0x4480;  // 1024.0 in bf16
}

extern "C" void kernel_launch(void* const* d_in, const int* in_sizes, int n_in,
                              void* d_out, int out_size, void* d_ws, size_t ws_size,
                              hipStream_t stream) {
  const void* x    = d_in[0];
  const void* wqkv = d_in[1];
  const void* bqkv = d_in[2];
  const void* wo   = d_in[3];
  const void* bo   = d_in[4];
  const unsigned* xprobe = (const unsigned*)d_in[0];

  const size_t need = ((size_t)M_ * QKVROW + (size_t)B_ * H_ * HD_ * S_) * 2;  // 64 MiB
  if (ws_size < need) {
    ws_sentinel<<<(out_size + 255) / 256, 256, 0, stream>>>((unsigned short*)d_out, out_size);
    return;
  }

  unsigned short* qkv = (unsigned short*)d_ws;            // 48 MiB: [4096][6144]
  unsigned short* Vt  = qkv + (size_t)M_ * QKVROW;        // 16 MiB: [b,h,hd,s]

  // qkv = x @ Wqkv^T + b   (A,B,bias follow input dtype; C is bf16 ws)
  gemm_bt_bias<<<dim3(QKVROW / 128, M_ / 128), 256, 0, stream>>>(
      x, wqkv, bqkv, qkv, QKVROW, 2048, 2048, 128, 1, 1, 1, 0, xprobe);
  // in-place RoPE on q,k; build Vt
  rope_vt<<<dim3(S_ / 64, H_, B_), 256, 0, stream>>>(qkv, Vt);
  // attention; ctx lands in the q slot of qkv
  attn<<<dim3(S_ / 128, B_ * H_), 256, 0, stream>>>(qkv, Vt);
  // out = ctx @ wo^T + b  (A is bf16 ws; B,bias follow input; C follows input)
  gemm_bt_bias<<<dim3(2048 / 128, M_ / 128), 256, 0, stream>>>(
      qkv, wo, bo, d_out, 2048, 2048, QKVROW, 384, 0, 1, 1, 1, xprobe);
}

// Round 5
// 654.116 us; speedup vs baseline: 1.2451x; 1.2451x over previous
//
#include <hip/hip_runtime.h>

#define B_ 2
#define S_ 2048
#define H_ 16
#define HD_ 128
#define QKVROW 6144   // 3*2048, row length of qkv activation
#define M_ 4096       // B_*S_

typedef float f32x4 __attribute__((ext_vector_type(4)));
typedef __bf16 bf16x8 __attribute__((ext_vector_type(8)));
typedef unsigned short ushortx8 __attribute__((ext_vector_type(8)));

__device__ __forceinline__ float bf2f(unsigned short u) {
  union { unsigned u; float f; } v;
  v.u = ((unsigned)u) << 16;
  return v.f;
}
__device__ __forceinline__ unsigned short f2bf(float f) {
  union { __bf16 b; unsigned short u; } c;
  c.b = (__bf16)f;  // native v_cvt path
  return c.u;
}
// 8 contiguous fp32 -> 8 bf16 ushorts (vector loads + native cvt)
__device__ __forceinline__ ushortx8 cvt8(const float* f) {
  const f32x4 lo = *(const f32x4*)f;
  const f32x4 hi = *(const f32x4*)(f + 4);
  ushortx8 o;
#pragma unroll
  for (int t = 0; t < 4; ++t) o[t] = f2bf(lo[t]);
#pragma unroll
  for (int t = 0; t < 4; ++t) o[4 + t] = f2bf(hi[t]);
  return o;
}
// async global->LDS, 16B/lane. LDS dest = wave-uniform base + lane*16.
__device__ __forceinline__ void async16(const unsigned short* g, unsigned short* l) {
  __builtin_amdgcn_global_load_lds(
      (const __attribute__((address_space(1))) unsigned int*)g,
      (__attribute__((address_space(3))) unsigned int*)l, 16, 0, 0);
}

// ---------------------------------------------------------------------------
// GEMM1: qkv[m,n] = sum_k x[m,k]*Wqkv[n,k] + b[n].  x,W,b fp32; C bf16.
// M=4096 N=6144 K=2048. 128x128 tile, BK=64. Reg-prefetch staging with
// fp32->bf16 cvt at load; XOR-swizzled LDS (16B units) -> conflict-free frags.
// ---------------------------------------------------------------------------
__global__ __launch_bounds__(256) void gemm1(
    const float* __restrict__ A, const float* __restrict__ Bm,
    const float* __restrict__ bias, unsigned short* __restrict__ C) {
  __shared__ unsigned short As[128 * 64];
  __shared__ unsigned short Bs[128 * 64];
  const int tid = threadIdx.x;
  const int lane = tid & 63, wave = tid >> 6;
  const int l15 = lane & 15, quad = lane >> 4;
  const int m0 = blockIdx.y * 128, n0 = blockIdx.x * 128;
  const int wr = (wave >> 1) * 64, wc = (wave & 1) * 64;

  f32x4 acc[4][4];
#pragma unroll
  for (int r = 0; r < 4; ++r)
#pragma unroll
    for (int c = 0; c < 4; ++c) acc[r][c] = (f32x4){0.f, 0.f, 0.f, 0.f};

  ushortx8 ra[4], rb[4];
#pragma unroll
  for (int p = 0; p < 4; ++p) {  // prefetch k0=0
    const int u = p * 256 + tid, row = u >> 3, cu = u & 7;
    ra[p] = cvt8(A + (size_t)(m0 + row) * 2048 + cu * 8);
    rb[p] = cvt8(Bm + (size_t)(n0 + row) * 2048 + cu * 8);
  }

  for (int k0 = 0; k0 < 2048; k0 += 64) {
    __syncthreads();  // prior iteration's frag reads done
#pragma unroll
    for (int p = 0; p < 4; ++p) {
      const int u = p * 256 + tid, row = u >> 3, cu = u & 7;
      const int ph = row * 64 + ((cu ^ (row & 7)) << 3);  // swizzled
      *(ushortx8*)&As[ph] = ra[p];
      *(ushortx8*)&Bs[ph] = rb[p];
    }
    __syncthreads();  // tiles visible
    if (k0 + 64 < 2048) {  // prefetch next tile (overlaps with MFMA below)
#pragma unroll
      for (int p = 0; p < 4; ++p) {
        const int u = p * 256 + tid, row = u >> 3, cu = u & 7;
        ra[p] = cvt8(A + (size_t)(m0 + row) * 2048 + k0 + 64 + cu * 8);
        rb[p] = cvt8(Bm + (size_t)(n0 + row) * 2048 + k0 + 64 + cu * 8);
      }
    }
#pragma unroll
    for (int s = 0; s < 2; ++s) {
      bf16x8 af[4], bf[4];
#pragma unroll
      for (int r = 0; r < 4; ++r) {
        const int row = wr + r * 16 + l15;
        af[r] = *(const bf16x8*)&As[row * 64 + (((s * 4 + quad) ^ (row & 7)) << 3)];
      }
#pragma unroll
      for (int c = 0; c < 4; ++c) {
        const int row = wc + c * 16 + l15;
        bf[c] = *(const bf16x8*)&Bs[row * 64 + (((s * 4 + quad) ^ (row & 7)) << 3)];
      }
#pragma unroll
      for (int r = 0; r < 4; ++r)
#pragma unroll
        for (int c = 0; c < 4; ++c)
          acc[r][c] = __builtin_amdgcn_mfma_f32_16x16x32_bf16(af[r], bf[c], acc[r][c], 0, 0, 0);
    }
  }

#pragma unroll
  for (int c = 0; c < 4; ++c) {
    const int col = n0 + wc + c * 16 + l15;
    const float bv = bias[col];
#pragma unroll
    for (int r = 0; r < 4; ++r) {
      const int row = m0 + wr + r * 16 + quad * 4;
#pragma unroll
      for (int i = 0; i < 4; ++i)
        C[(size_t)(row + i) * QKVROW + col] = f2bf(acc[r][c][i] + bv);
    }
  }
}

// ---------------------------------------------------------------------------
// In-place deinterleave+RoPE on q,k slots of qkv [b,s,h,3,hd] (q pre-scaled
// by hd^-0.5); Vt [b,h,hd,s] from the v slot. Unchanged from round 4 (works).
// ---------------------------------------------------------------------------
__global__ __launch_bounds__(256) void rope_vt(
    unsigned short* qkv, unsigned short* __restrict__ Vt) {
  __shared__ unsigned short vs[64 * 136];
  const int b = blockIdx.z, h = blockIdx.y, s0 = blockIdx.x * 64;
  const int tid = threadIdx.x;
  const int r = tid >> 2, cpart = (tid & 3) * 32;
  const int s = s0 + r;
  unsigned short* base = qkv + (size_t)(b * S_ + s) * QKVROW + h * 384;
  const int j0 = cpart >> 1;

  ushortx8 ivq[4], ivk[4], ivv[4];
#pragma unroll
  for (int i = 0; i < 4; ++i) {
    ivq[i] = *(const ushortx8*)&base[cpart + i * 8];
    ivk[i] = *(const ushortx8*)&base[128 + cpart + i * 8];
    ivv[i] = *(const ushortx8*)&base[256 + cpart + i * 8];
  }

  float cs[16], sn[16];
#pragma unroll
  for (int t = 0; t < 16; ++t) {
    const float invf = expf(-(float)(j0 + t) * 0.14391156831212787f);  // ln(1e4)/64
    sincosf((float)s * invf, &sn[t], &cs[t]);
  }

  __syncthreads();  // all reads of q/k rows done before anyone writes them

#pragma unroll
  for (int which = 0; which < 2; ++which) {
    const ushortx8* iv = (which == 0) ? ivq : ivk;
    const float scale = (which == 0) ? 0.08838834764831845f : 1.0f;
    ushortx8 o1a, o1b, o2a, o2b;
#pragma unroll
    for (int t = 0; t < 16; ++t) {
      const float x1 = bf2f(iv[(2 * t) >> 3][(2 * t) & 7]);
      const float x2 = bf2f(iv[(2 * t + 1) >> 3][(2 * t + 1) & 7]);
      const unsigned short r1 = f2bf((x1 * cs[t] - x2 * sn[t]) * scale);
      const unsigned short r2 = f2bf((x2 * cs[t] + x1 * sn[t]) * scale);
      if (t < 8) { o1a[t] = r1; o2a[t] = r2; }
      else       { o1b[t - 8] = r1; o2b[t - 8] = r2; }
    }
    unsigned short* out = base + which * 128;
    *(ushortx8*)&out[j0] = o1a;
    *(ushortx8*)&out[j0 + 8] = o1b;
    *(ushortx8*)&out[64 + j0] = o2a;
    *(ushortx8*)&out[64 + j0 + 8] = o2b;
  }

#pragma unroll
  for (int i = 0; i < 4; ++i)
    *(ushortx8*)&vs[r * 136 + cpart + i * 8] = ivv[i];
  __syncthreads();
  const size_t vtb = (size_t)(b * H_ + h) * HD_ * S_ + s0;
#pragma unroll
  for (int it = 0; it < 4; ++it) {
    const int a = tid + it * 256;
    const int d = a >> 3, sc = (a & 7) * 8;
    ushortx8 o;
#pragma unroll
    for (int t = 0; t < 8; ++t) o[t] = vs[(sc + t) * 136 + d];
    *(ushortx8*)&Vt[vtb + (size_t)d * S_ + sc] = o;
  }
}

// ---------------------------------------------------------------------------
// Flash attention, causal. grid (16, 32), 256 threads. K/V staged via
// global_load_lds (m97 structure); P overlay swizzled (conflict-free A-frag
// reads). qt reversed so long blocks dispatch first. ctx -> q slot.
// ---------------------------------------------------------------------------
__global__ __launch_bounds__(256) void attn(
    unsigned short* qkv, const unsigned short* __restrict__ Vt) {
  __shared__ unsigned short Ks[128 * 128];  // 32KB (P overlays here later)
  __shared__ unsigned short Vs[128 * 128];  // 32KB
  const int qt = (S_ / 128 - 1) - blockIdx.x;  // long blocks first
  const int bh = blockIdx.y;
  const int b = bh >> 4, h = bh & 15;
  const int tid = threadIdx.x, lane = tid & 63, wave = tid >> 6;
  const int l15 = lane & 15, quad = lane >> 4;

  unsigned short* qh = qkv + (size_t)b * S_ * QKVROW + h * 384;
  const unsigned short* Vb = Vt + (size_t)bh * HD_ * S_;

  bf16x8 aq[2][4];
#pragma unroll
  for (int rt = 0; rt < 2; ++rt)
#pragma unroll
    for (int ks = 0; ks < 4; ++ks)
      aq[rt][ks] = *(const bf16x8*)&qh[(size_t)(qt * 128 + wave * 32 + rt * 16 + l15) * QKVROW +
                                       ks * 32 + quad * 8];

  f32x4 o[2][8];
  float mrow[2][4], lrow[2][4];
#pragma unroll
  for (int rt = 0; rt < 2; ++rt) {
#pragma unroll
    for (int ct = 0; ct < 8; ++ct) o[rt][ct] = (f32x4){0.f, 0.f, 0.f, 0.f};
#pragma unroll
    for (int i = 0; i < 4; ++i) { mrow[rt][i] = -1e30f; lrow[rt][i] = 0.f; }
  }

  for (int j = 0; j <= qt; ++j) {
    // async stage K tile [kv 128 x 128] and Vt tile [d 128 x kv 128], linear
#pragma unroll
    for (int i = 0; i < 8; ++i) {
      const int c0 = wave * 512 + i * 64;
      const int u = c0 + lane;
      const int row = u >> 4, cu = u & 15;  // 16 units (256B) per LDS row
      async16(qh + (size_t)(j * 128 + row) * QKVROW + 128 + cu * 8, &Ks[c0 * 8]);
      async16(Vb + (size_t)row * S_ + j * 128 + cu * 8, &Vs[c0 * 8]);
    }
    __syncthreads();  // drains vmcnt -> tiles valid

    // S = Q K^T (Q pre-scaled)
    f32x4 sacc[2][8];
#pragma unroll
    for (int rt = 0; rt < 2; ++rt)
#pragma unroll
      for (int ct = 0; ct < 8; ++ct) sacc[rt][ct] = (f32x4){0.f, 0.f, 0.f, 0.f};
#pragma unroll
    for (int ks = 0; ks < 4; ++ks) {
      bf16x8 bk[8];
#pragma unroll
      for (int ct = 0; ct < 8; ++ct)
        bk[ct] = *(const bf16x8*)&Ks[(ct * 16 + l15) * 128 + (ks * 4 + quad) * 8];
#pragma unroll
      for (int rt = 0; rt < 2; ++rt)
#pragma unroll
        for (int ct = 0; ct < 8; ++ct)
          sacc[rt][ct] = __builtin_amdgcn_mfma_f32_16x16x32_bf16(aq[rt][ks], bk[ct], sacc[rt][ct], 0, 0, 0);
    }

    if (j == qt) {  // causal mask on diagonal tile
#pragma unroll
      for (int rt = 0; rt < 2; ++rt)
#pragma unroll
        for (int ct = 0; ct < 8; ++ct)
#pragma unroll
          for (int i = 0; i < 4; ++i) {
            const int row = wave * 32 + rt * 16 + quad * 4 + i;
            const int col = ct * 16 + l15;
            if (col > row) sacc[rt][ct][i] = -1e30f;
          }
    }

    // online softmax
    float alpha[2][4];
#pragma unroll
    for (int rt = 0; rt < 2; ++rt)
#pragma unroll
      for (int i = 0; i < 4; ++i) {
        float m = sacc[rt][0][i];
#pragma unroll
        for (int ct = 1; ct < 8; ++ct) m = fmaxf(m, sacc[rt][ct][i]);
#pragma unroll
        for (int off = 1; off < 16; off <<= 1) m = fmaxf(m, __shfl_xor(m, off));
        const float mn = fmaxf(mrow[rt][i], m);
        alpha[rt][i] = __expf(mrow[rt][i] - mn);
        mrow[rt][i] = mn;
        float rsum = 0.f;
#pragma unroll
        for (int ct = 0; ct < 8; ++ct) {
          const float p = __expf(sacc[rt][ct][i] - mn);
          sacc[rt][ct][i] = p;
          rsum += p;
        }
#pragma unroll
        for (int off = 1; off < 16; off <<= 1) rsum += __shfl_xor(rsum, off);
        lrow[rt][i] = lrow[rt][i] * alpha[rt][i] + rsum;
#pragma unroll
        for (int ct = 0; ct < 8; ++ct) o[rt][ct][i] *= alpha[rt][i];
      }

    __syncthreads();  // all waves done reading Ks; safe to overlay P
    // P store, XOR-swizzled on 16B units within each 32x128 wave region
    unsigned short* Ps = &Ks[wave * 4096];
#pragma unroll
    for (int rt = 0; rt < 2; ++rt)
#pragma unroll
      for (int ct = 0; ct < 8; ++ct)
#pragma unroll
        for (int i = 0; i < 4; ++i) {
          const int row = rt * 16 + quad * 4 + i;
          const int col = ct * 16 + l15;
          Ps[row * 128 + ((((col >> 3) ^ (row & 15)) << 3) | (col & 7))] =
              f2bf(sacc[rt][ct][i]);
        }

    // O += P * V
#pragma unroll
    for (int ks = 0; ks < 4; ++ks) {
      bf16x8 ap[2];
#pragma unroll
      for (int rt = 0; rt < 2; ++rt) {
        const int row = rt * 16 + l15;
        ap[rt] = *(const bf16x8*)&Ps[row * 128 + (((ks * 4 + quad) ^ (row & 15)) << 3)];
      }
      bf16x8 bv[8];
#pragma unroll
      for (int ct = 0; ct < 8; ++ct)
        bv[ct] = *(const bf16x8*)&Vs[(ct * 16 + l15) * 128 + (ks * 4 + quad) * 8];
#pragma unroll
      for (int rt = 0; rt < 2; ++rt)
#pragma unroll
        for (int ct = 0; ct < 8; ++ct)
          o[rt][ct] = __builtin_amdgcn_mfma_f32_16x16x32_bf16(ap[rt], bv[ct], o[rt][ct], 0, 0, 0);
    }
    __syncthreads();  // P/V reads done before next iter's async staging
  }

  // write ctx into the (consumed, block-private) q slot
#pragma unroll
  for (int rt = 0; rt < 2; ++rt) {
    float inv[4];
#pragma unroll
    for (int i = 0; i < 4; ++i) inv[i] = 1.0f / lrow[rt][i];
#pragma unroll
    for (int ct = 0; ct < 8; ++ct)
#pragma unroll
      for (int i = 0; i < 4; ++i) {
        const int srow = qt * 128 + wave * 32 + rt * 16 + quad * 4 + i;
        qh[(size_t)srow * QKVROW + ct * 16 + l15] = f2bf(o[rt][ct][i] * inv[i]);
      }
  }
}

// ---------------------------------------------------------------------------
// GEMM2: out[m,n] = sum_k ctx[m,k]*wo[n,k] + bo[n]. ctx bf16 strided in qkv
// (elem(m,k) at m*6144 + (k>>7)*384 + (k&127)); wo,bo fp32; out fp32.
// A staged via global_load_lds (linear LDS); B reg-prefetch + cvt + swizzle.
// ---------------------------------------------------------------------------
__global__ __launch_bounds__(256) void gemm2(
    const unsigned short* __restrict__ A, const float* __restrict__ Bm,
    const float* __restrict__ bias, float* __restrict__ C) {
  __shared__ unsigned short As[128 * 64];
  __shared__ unsigned short Bs[128 * 64];
  const int tid = threadIdx.x;
  const int lane = tid & 63, wave = tid >> 6;
  const int l15 = lane & 15, quad = lane >> 4;
  const int m0 = blockIdx.y * 128, n0 = blockIdx.x * 128;
  const int wr = (wave >> 1) * 64, wc = (wave & 1) * 64;

  f32x4 acc[4][4];
#pragma unroll
  for (int r = 0; r < 4; ++r)
#pragma unroll
    for (int c = 0; c < 4; ++c) acc[r][c] = (f32x4){0.f, 0.f, 0.f, 0.f};

  ushortx8 rb[4];
#pragma unroll
  for (int p = 0; p < 4; ++p) {  // prefetch B k0=0
    const int u = p * 256 + tid, row = u >> 3, cu = u & 7;
    rb[p] = cvt8(Bm + (size_t)(n0 + row) * 2048 + cu * 8);
  }

  for (int k0 = 0; k0 < 2048; k0 += 64) {
    const int kh = ((k0 >> 7) * 384) + (k0 & 127);
    __syncthreads();  // prior frag reads done
    // A tile via async (linear LDS fill)
#pragma unroll
    for (int i = 0; i < 4; ++i) {
      const int c0 = wave * 256 + i * 64;
      const int u = c0 + lane, row = u >> 3, cu = u & 7;
      async16(A + (size_t)(m0 + row) * QKVROW + kh + cu * 8, &As[c0 * 8]);
    }
    // B tile from prefetched regs, swizzled
#pragma unroll
    for (int p = 0; p < 4; ++p) {
      const int u = p * 256 + tid, row = u >> 3, cu = u & 7;
      *(ushortx8*)&Bs[row * 64 + ((cu ^ (row & 7)) << 3)] = rb[p];
    }
    __syncthreads();  // drains vmcnt(async) + lgkm
    if (k0 + 64 < 2048) {
#pragma unroll
      for (int p = 0; p < 4; ++p) {
        const int u = p * 256 + tid, row = u >> 3, cu = u & 7;
        rb[p] = cvt8(Bm + (size_t)(n0 + row) * 2048 + k0 + 64 + cu * 8);
      }
    }
#pragma unroll
    for (int s = 0; s < 2; ++s) {
      bf16x8 af[4], bf[4];
#pragma unroll
      for (int r = 0; r < 4; ++r)
        af[r] = *(const bf16x8*)&As[(wr + r * 16 + l15) * 64 + (s * 4 + quad) * 8];
#pragma unroll
      for (int c = 0; c < 4; ++c) {
        const int row = wc + c * 16 + l15;
        bf[c] = *(const bf16x8*)&Bs[row * 64 + (((s * 4 + quad) ^ (row & 7)) << 3)];
      }
#pragma unroll
      for (int r = 0; r < 4; ++r)
#pragma unroll
        for (int c = 0; c < 4; ++c)
          acc[r][c] = __builtin_amdgcn_mfma_f32_16x16x32_bf16(af[r], bf[c], acc[r][c], 0, 0, 0);
    }
  }

#pragma unroll
  for (int c = 0; c < 4; ++c) {
    const int col = n0 + wc + c * 16 + l15;
    const float bv = bias[col];
#pragma unroll
    for (int r = 0; r < 4; ++r) {
      const int row = m0 + wr + r * 16 + quad * 4;
#pragma unroll
      for (int i = 0; i < 4; ++i)
        C[(size_t)(row + i) * 2048 + col] = acc[r][c][i] + bv;
    }
  }
}

extern "C" void kernel_launch(void* const* d_in, const int* in_sizes, int n_in,
                              void* d_out, int out_size, void* d_ws, size_t ws_size,
                              hipStream_t stream) {
  const float* x    = (const float*)d_in[0];
  const float* wqkv = (const float*)d_in[1];
  const float* bqkv = (const float*)d_in[2];
  const float* wo   = (const float*)d_in[3];
  const float* bo   = (const float*)d_in[4];
  float* out = (float*)d_out;

  unsigned short* qkv = (unsigned short*)d_ws;            // 50.3 MB [4096][6144]
  unsigned short* Vt  = qkv + (size_t)M_ * QKVROW;        // 16.8 MB [b,h,hd,s]

  gemm1<<<dim3(QKVROW / 128, M_ / 128), 256, 0, stream>>>(x, wqkv, bqkv, qkv);
  rope_vt<<<dim3(S_ / 64, H_, B_), 256, 0, stream>>>(qkv, Vt);
  attn<<<dim3(S_ / 128, B_ * H_), 256, 0, stream>>>(qkv, Vt);
  gemm2<<<dim3(2048 / 128, M_ / 128), 256, 0, stream>>>(qkv, wo, bo, out);
}

// Round 6
// 490.180 us; speedup vs baseline: 1.6616x; 1.3344x over previous
//
#include <hip/hip_runtime.h>

#define B_ 2
#define S_ 2048
#define H_ 16
#define HD_ 128
#define QKVROW 6144   // 3*2048, row length of qkv activation
#define M_ 4096       // B_*S_

typedef float f32x4 __attribute__((ext_vector_type(4)));
typedef __bf16 bf16x8 __attribute__((ext_vector_type(8)));
typedef unsigned short ushortx8 __attribute__((ext_vector_type(8)));

__device__ __forceinline__ float bf2f(unsigned short u) {
  union { unsigned u; float f; } v;
  v.u = ((unsigned)u) << 16;
  return v.f;
}
__device__ __forceinline__ unsigned short f2bf(float f) {
  union { __bf16 b; unsigned short u; } c;
  c.b = (__bf16)f;  // native v_cvt path
  return c.u;
}
// 8 contiguous fp32 -> 8 bf16 ushorts (vector loads + native cvt)
__device__ __forceinline__ ushortx8 cvt8(const float* f) {
  const f32x4 lo = *(const f32x4*)f;
  const f32x4 hi = *(const f32x4*)(f + 4);
  ushortx8 o;
#pragma unroll
  for (int t = 0; t < 4; ++t) o[t] = f2bf(lo[t]);
#pragma unroll
  for (int t = 0; t < 4; ++t) o[4 + t] = f2bf(hi[t]);
  return o;
}
// async global->LDS, 16B/lane. LDS dest = wave-uniform base + lane*16.
__device__ __forceinline__ void async16(const unsigned short* g, unsigned short* l) {
  __builtin_amdgcn_global_load_lds(
      (const __attribute__((address_space(1))) unsigned int*)g,
      (__attribute__((address_space(3))) unsigned int*)l, 16, 0, 0);
}

// ---------------------------------------------------------------------------
// GEMM1: qkv[m,n] = sum_k x[m,k]*Wqkv[n,k] + b[n].  x,W,b fp32; C bf16.
// Unchanged from round 5 (reg-prefetch + cvt + swizzled LDS).
// ---------------------------------------------------------------------------
__global__ __launch_bounds__(256) void gemm1(
    const float* __restrict__ A, const float* __restrict__ Bm,
    const float* __restrict__ bias, unsigned short* __restrict__ C) {
  __shared__ unsigned short As[128 * 64];
  __shared__ unsigned short Bs[128 * 64];
  const int tid = threadIdx.x;
  const int lane = tid & 63, wave = tid >> 6;
  const int l15 = lane & 15, quad = lane >> 4;
  const int m0 = blockIdx.y * 128, n0 = blockIdx.x * 128;
  const int wr = (wave >> 1) * 64, wc = (wave & 1) * 64;

  f32x4 acc[4][4];
#pragma unroll
  for (int r = 0; r < 4; ++r)
#pragma unroll
    for (int c = 0; c < 4; ++c) acc[r][c] = (f32x4){0.f, 0.f, 0.f, 0.f};

  ushortx8 ra[4], rb[4];
#pragma unroll
  for (int p = 0; p < 4; ++p) {  // prefetch k0=0
    const int u = p * 256 + tid, row = u >> 3, cu = u & 7;
    ra[p] = cvt8(A + (size_t)(m0 + row) * 2048 + cu * 8);
    rb[p] = cvt8(Bm + (size_t)(n0 + row) * 2048 + cu * 8);
  }

  for (int k0 = 0; k0 < 2048; k0 += 64) {
    __syncthreads();  // prior iteration's frag reads done
#pragma unroll
    for (int p = 0; p < 4; ++p) {
      const int u = p * 256 + tid, row = u >> 3, cu = u & 7;
      const int ph = row * 64 + ((cu ^ (row & 7)) << 3);  // swizzled
      *(ushortx8*)&As[ph] = ra[p];
      *(ushortx8*)&Bs[ph] = rb[p];
    }
    __syncthreads();  // tiles visible
    if (k0 + 64 < 2048) {  // prefetch next tile (overlaps with MFMA below)
#pragma unroll
      for (int p = 0; p < 4; ++p) {
        const int u = p * 256 + tid, row = u >> 3, cu = u & 7;
        ra[p] = cvt8(A + (size_t)(m0 + row) * 2048 + k0 + 64 + cu * 8);
        rb[p] = cvt8(Bm + (size_t)(n0 + row) * 2048 + k0 + 64 + cu * 8);
      }
    }
#pragma unroll
    for (int s = 0; s < 2; ++s) {
      bf16x8 af[4], bf[4];
#pragma unroll
      for (int r = 0; r < 4; ++r) {
        const int row = wr + r * 16 + l15;
        af[r] = *(const bf16x8*)&As[row * 64 + (((s * 4 + quad) ^ (row & 7)) << 3)];
      }
#pragma unroll
      for (int c = 0; c < 4; ++c) {
        const int row = wc + c * 16 + l15;
        bf[c] = *(const bf16x8*)&Bs[row * 64 + (((s * 4 + quad) ^ (row & 7)) << 3)];
      }
#pragma unroll
      for (int r = 0; r < 4; ++r)
#pragma unroll
        for (int c = 0; c < 4; ++c)
          acc[r][c] = __builtin_amdgcn_mfma_f32_16x16x32_bf16(af[r], bf[c], acc[r][c], 0, 0, 0);
    }
  }

#pragma unroll
  for (int c = 0; c < 4; ++c) {
    const int col = n0 + wc + c * 16 + l15;
    const float bv = bias[col];
#pragma unroll
    for (int r = 0; r < 4; ++r) {
      const int row = m0 + wr + r * 16 + quad * 4;
#pragma unroll
      for (int i = 0; i < 4; ++i)
        C[(size_t)(row + i) * QKVROW + col] = f2bf(acc[r][c][i] + bv);
    }
  }
}

// ---------------------------------------------------------------------------
// In-place deinterleave+RoPE on q,k slots of qkv (q pre-scaled by hd^-0.5);
// Vt [b,h,hd,s] from the v slot. Unchanged (works, not hot).
// ---------------------------------------------------------------------------
__global__ __launch_bounds__(256) void rope_vt(
    unsigned short* qkv, unsigned short* __restrict__ Vt) {
  __shared__ unsigned short vs[64 * 136];
  const int b = blockIdx.z, h = blockIdx.y, s0 = blockIdx.x * 64;
  const int tid = threadIdx.x;
  const int r = tid >> 2, cpart = (tid & 3) * 32;
  const int s = s0 + r;
  unsigned short* base = qkv + (size_t)(b * S_ + s) * QKVROW + h * 384;
  const int j0 = cpart >> 1;

  ushortx8 ivq[4], ivk[4], ivv[4];
#pragma unroll
  for (int i = 0; i < 4; ++i) {
    ivq[i] = *(const ushortx8*)&base[cpart + i * 8];
    ivk[i] = *(const ushortx8*)&base[128 + cpart + i * 8];
    ivv[i] = *(const ushortx8*)&base[256 + cpart + i * 8];
  }

  float cs[16], sn[16];
#pragma unroll
  for (int t = 0; t < 16; ++t) {
    const float invf = expf(-(float)(j0 + t) * 0.14391156831212787f);  // ln(1e4)/64
    sincosf((float)s * invf, &sn[t], &cs[t]);
  }

  __syncthreads();  // all reads of q/k rows done before anyone writes them

#pragma unroll
  for (int which = 0; which < 2; ++which) {
    const ushortx8* iv = (which == 0) ? ivq : ivk;
    const float scale = (which == 0) ? 0.08838834764831845f : 1.0f;
    ushortx8 o1a, o1b, o2a, o2b;
#pragma unroll
    for (int t = 0; t < 16; ++t) {
      const float x1 = bf2f(iv[(2 * t) >> 3][(2 * t) & 7]);
      const float x2 = bf2f(iv[(2 * t + 1) >> 3][(2 * t + 1) & 7]);
      const unsigned short r1 = f2bf((x1 * cs[t] - x2 * sn[t]) * scale);
      const unsigned short r2 = f2bf((x2 * cs[t] + x1 * sn[t]) * scale);
      if (t < 8) { o1a[t] = r1; o2a[t] = r2; }
      else       { o1b[t - 8] = r1; o2b[t - 8] = r2; }
    }
    unsigned short* out = base + which * 128;
    *(ushortx8*)&out[j0] = o1a;
    *(ushortx8*)&out[j0 + 8] = o1b;
    *(ushortx8*)&out[64 + j0] = o2a;
    *(ushortx8*)&out[64 + j0 + 8] = o2b;
  }

#pragma unroll
  for (int i = 0; i < 4; ++i)
    *(ushortx8*)&vs[r * 136 + cpart + i * 8] = ivv[i];
  __syncthreads();
  const size_t vtb = (size_t)(b * H_ + h) * HD_ * S_ + s0;
#pragma unroll
  for (int it = 0; it < 4; ++it) {
    const int a = tid + it * 256;
    const int d = a >> 3, sc = (a & 7) * 8;
    ushortx8 o;
#pragma unroll
    for (int t = 0; t < 8; ++t) o[t] = vs[(sc + t) * 136 + d];
    *(ushortx8*)&Vt[vtb + (size_t)d * S_ + sc] = o;
  }
}

// ---------------------------------------------------------------------------
// Flash attention v3, causal. grid (8, 32), 512 threads (8 waves).
// Load-balanced: block p handles q-tiles p and 15-p (uniform 34 kv-64 iters).
// Each wave owns 16 q-rows. K tile [64 kv][128 d] pitch 136; Vt tile
// [128 d][64 kv] pitch 72; P per-wave strip [16][72] (no PV barrier).
// Classic reg staging (2+2 ushortx8/thread) with next-tile prefetch.
// ctx written into the consumed, block-private q slot.
// ---------------------------------------------------------------------------
__global__ __launch_bounds__(512) void attn(
    unsigned short* qkv, const unsigned short* __restrict__ Vt) {
  __shared__ unsigned short Ks[64 * 136];   // 17.4 KB
  __shared__ unsigned short Vs[128 * 72];   // 18.4 KB
  __shared__ unsigned short Ps[8 * 16 * 72];// 18.4 KB (per-wave strips)
  const int p = blockIdx.x, bh = blockIdx.y;
  const int b = bh >> 4, h = bh & 15;
  const int tid = threadIdx.x, lane = tid & 63, wave = tid >> 6;
  const int l15 = lane & 15, quad = lane >> 4;

  unsigned short* qh = qkv + (size_t)b * S_ * QKVROW + h * 384;
  const unsigned short* Vb = Vt + (size_t)bh * HD_ * S_;
  unsigned short* Pw = &Ps[wave * 16 * 72];

  ushortx8 rk[2], rv[2];
  auto pref = [&](int j) {  // stage kv-64 tile j into regs
#pragma unroll
    for (int t = 0; t < 2; ++t) {
      const int uk = t * 512 + tid;
      const int krow = uk >> 4, kcu = uk & 15;  // 64 rows x 16 units
      rk[t] = *(const ushortx8*)(qh + (size_t)(j * 64 + krow) * QKVROW + 128 + kcu * 8);
      const int vrow = uk >> 3, vcu = uk & 7;   // 128 rows x 8 units
      rv[t] = *(const ushortx8*)(Vb + (size_t)vrow * S_ + j * 64 + vcu * 8);
    }
  };
  pref(0);

#pragma unroll
  for (int half = 0; half < 2; ++half) {
    const int qt = half ? 15 - p : p;   // short tile first, then long
    const int jN = 2 * qt + 2;          // kv-64 tiles needed

    bf16x8 aq[4];
#pragma unroll
    for (int ks = 0; ks < 4; ++ks)
      aq[ks] = *(const bf16x8*)&qh[(size_t)(qt * 128 + wave * 16 + l15) * QKVROW +
                                   ks * 32 + quad * 8];

    f32x4 o[8];
    float mrow[4], lrow[4];
#pragma unroll
    for (int ct = 0; ct < 8; ++ct) o[ct] = (f32x4){0.f, 0.f, 0.f, 0.f};
#pragma unroll
    for (int i = 0; i < 4; ++i) { mrow[i] = -1e30f; lrow[i] = 0.f; }

    for (int j = 0; j < jN; ++j) {
      __syncthreads();  // all waves done reading Ks/Vs of previous tile
#pragma unroll
      for (int t = 0; t < 2; ++t) {
        const int uk = t * 512 + tid;
        *(ushortx8*)&Ks[(uk >> 4) * 136 + (uk & 15) * 8] = rk[t];
        *(ushortx8*)&Vs[(uk >> 3) * 72 + (uk & 7) * 8] = rv[t];
      }
      __syncthreads();  // tiles visible

      const int jn = (j + 1 < jN) ? j + 1 : (half == 0 ? 0 : -1);
      if (jn >= 0) pref(jn);  // overlaps MFMA/softmax below

      // S = Q K^T over this kv-64 tile (Q pre-scaled by hd^-0.5)
      f32x4 sacc[4];
#pragma unroll
      for (int ct = 0; ct < 4; ++ct) sacc[ct] = (f32x4){0.f, 0.f, 0.f, 0.f};
#pragma unroll
      for (int ks = 0; ks < 4; ++ks) {
        bf16x8 bk[4];
#pragma unroll
        for (int ct = 0; ct < 4; ++ct)
          bk[ct] = *(const bf16x8*)&Ks[(ct * 16 + l15) * 136 + ks * 32 + quad * 8];
#pragma unroll
        for (int ct = 0; ct < 4; ++ct)
          sacc[ct] = __builtin_amdgcn_mfma_f32_16x16x32_bf16(aq[ks], bk[ct], sacc[ct], 0, 0, 0);
      }

      if (j >= 2 * qt) {  // diagonal region: mask gcol > grow
#pragma unroll
        for (int ct = 0; ct < 4; ++ct)
#pragma unroll
          for (int i = 0; i < 4; ++i) {
            const int grow = qt * 128 + wave * 16 + quad * 4 + i;
            const int gcol = j * 64 + ct * 16 + l15;
            if (gcol > grow) sacc[ct][i] = -1e30f;
          }
      }

      // online softmax (16 rows/wave = quad*4+i; reduce over 16 lanes)
#pragma unroll
      for (int i = 0; i < 4; ++i) {
        float m = sacc[0][i];
#pragma unroll
        for (int ct = 1; ct < 4; ++ct) m = fmaxf(m, sacc[ct][i]);
#pragma unroll
        for (int off = 1; off < 16; off <<= 1) m = fmaxf(m, __shfl_xor(m, off));
        const float mn = fmaxf(mrow[i], m);
        const float alpha = __expf(mrow[i] - mn);
        mrow[i] = mn;
        float rsum = 0.f;
#pragma unroll
        for (int ct = 0; ct < 4; ++ct) {
          const float pv = __expf(sacc[ct][i] - mn);
          sacc[ct][i] = pv;
          rsum += pv;
        }
#pragma unroll
        for (int off = 1; off < 16; off <<= 1) rsum += __shfl_xor(rsum, off);
        lrow[i] = lrow[i] * alpha + rsum;
#pragma unroll
        for (int ct = 0; ct < 8; ++ct) o[ct][i] *= alpha;
      }

      // P into wave-private strip (C-layout -> A-layout); no barrier needed
#pragma unroll
      for (int ct = 0; ct < 4; ++ct)
#pragma unroll
        for (int i = 0; i < 4; ++i)
          Pw[(quad * 4 + i) * 72 + ct * 16 + l15] = f2bf(sacc[ct][i]);

      // O += P * V
#pragma unroll
      for (int ks = 0; ks < 2; ++ks) {
        const bf16x8 ap = *(const bf16x8*)&Pw[l15 * 72 + ks * 32 + quad * 8];
        bf16x8 bv[8];
#pragma unroll
        for (int ct = 0; ct < 8; ++ct)
          bv[ct] = *(const bf16x8*)&Vs[(ct * 16 + l15) * 72 + ks * 32 + quad * 8];
#pragma unroll
        for (int ct = 0; ct < 8; ++ct)
          o[ct] = __builtin_amdgcn_mfma_f32_16x16x32_bf16(ap, bv[ct], o[ct], 0, 0, 0);
      }
    }

    // write ctx into the (consumed, block-private) q slot
    float inv[4];
#pragma unroll
    for (int i = 0; i < 4; ++i) inv[i] = 1.0f / lrow[i];
#pragma unroll
    for (int ct = 0; ct < 8; ++ct)
#pragma unroll
      for (int i = 0; i < 4; ++i) {
        const int srow = qt * 128 + wave * 16 + quad * 4 + i;
        qh[(size_t)srow * QKVROW + ct * 16 + l15] = f2bf(o[ct][i] * inv[i]);
      }
  }
}

// ---------------------------------------------------------------------------
// GEMM2: out[m,n] = sum_k ctx[m,k]*wo[n,k] + bo[n]. Unchanged from round 5.
// ---------------------------------------------------------------------------
__global__ __launch_bounds__(256) void gemm2(
    const unsigned short* __restrict__ A, const float* __restrict__ Bm,
    const float* __restrict__ bias, float* __restrict__ C) {
  __shared__ unsigned short As[128 * 64];
  __shared__ unsigned short Bs[128 * 64];
  const int tid = threadIdx.x;
  const int lane = tid & 63, wave = tid >> 6;
  const int l15 = lane & 15, quad = lane >> 4;
  const int m0 = blockIdx.y * 128, n0 = blockIdx.x * 128;
  const int wr = (wave >> 1) * 64, wc = (wave & 1) * 64;

  f32x4 acc[4][4];
#pragma unroll
  for (int r = 0; r < 4; ++r)
#pragma unroll
    for (int c = 0; c < 4; ++c) acc[r][c] = (f32x4){0.f, 0.f, 0.f, 0.f};

  ushortx8 rb[4];
#pragma unroll
  for (int p = 0; p < 4; ++p) {  // prefetch B k0=0
    const int u = p * 256 + tid, row = u >> 3, cu = u & 7;
    rb[p] = cvt8(Bm + (size_t)(n0 + row) * 2048 + cu * 8);
  }

  for (int k0 = 0; k0 < 2048; k0 += 64) {
    const int kh = ((k0 >> 7) * 384) + (k0 & 127);
    __syncthreads();  // prior frag reads done
#pragma unroll
    for (int i = 0; i < 4; ++i) {
      const int c0 = wave * 256 + i * 64;
      const int u = c0 + lane, row = u >> 3, cu = u & 7;
      async16(A + (size_t)(m0 + row) * QKVROW + kh + cu * 8, &As[c0 * 8]);
    }
#pragma unroll
    for (int p = 0; p < 4; ++p) {
      const int u = p * 256 + tid, row = u >> 3, cu = u & 7;
      *(ushortx8*)&Bs[row * 64 + ((cu ^ (row & 7)) << 3)] = rb[p];
    }
    __syncthreads();  // drains vmcnt(async) + lgkm
    if (k0 + 64 < 2048) {
#pragma unroll
      for (int p = 0; p < 4; ++p) {
        const int u = p * 256 + tid, row = u >> 3, cu = u & 7;
        rb[p] = cvt8(Bm + (size_t)(n0 + row) * 2048 + k0 + 64 + cu * 8);
      }
    }
#pragma unroll
    for (int s = 0; s < 2; ++s) {
      bf16x8 af[4], bf[4];
#pragma unroll
      for (int r = 0; r < 4; ++r)
        af[r] = *(const bf16x8*)&As[(wr + r * 16 + l15) * 64 + (s * 4 + quad) * 8];
#pragma unroll
      for (int c = 0; c < 4; ++c) {
        const int row = wc + c * 16 + l15;
        bf[c] = *(const bf16x8*)&Bs[row * 64 + (((s * 4 + quad) ^ (row & 7)) << 3)];
      }
#pragma unroll
      for (int r = 0; r < 4; ++r)
#pragma unroll
        for (int c = 0; c < 4; ++c)
          acc[r][c] = __builtin_amdgcn_mfma_f32_16x16x32_bf16(af[r], bf[c], acc[r][c], 0, 0, 0);
    }
  }

#pragma unroll
  for (int c = 0; c < 4; ++c) {
    const int col = n0 + wc + c * 16 + l15;
    const float bv = bias[col];
#pragma unroll
    for (int r = 0; r < 4; ++r) {
      const int row = m0 + wr + r * 16 + quad * 4;
#pragma unroll
      for (int i = 0; i < 4; ++i)
        C[(size_t)(row + i) * 2048 + col] = acc[r][c][i] + bv;
    }
  }
}

extern "C" void kernel_launch(void* const* d_in, const int* in_sizes, int n_in,
                              void* d_out, int out_size, void* d_ws, size_t ws_size,
                              hipStream_t stream) {
  const float* x    = (const float*)d_in[0];
  const float* wqkv = (const float*)d_in[1];
  const float* bqkv = (const float*)d_in[2];
  const float* wo   = (const float*)d_in[3];
  const float* bo   = (const float*)d_in[4];
  float* out = (float*)d_out;

  unsigned short* qkv = (unsigned short*)d_ws;            // 50.3 MB [4096][6144]
  unsigned short* Vt  = qkv + (size_t)M_ * QKVROW;        // 16.8 MB [b,h,hd,s]

  gemm1<<<dim3(QKVROW / 128, M_ / 128), 256, 0, stream>>>(x, wqkv, bqkv, qkv);
  rope_vt<<<dim3(S_ / 64, H_, B_), 256, 0, stream>>>(qkv, Vt);
  attn<<<dim3(8, B_ * H_), 512, 0, stream>>>(qkv, Vt);
  gemm2<<<dim3(2048 / 128, M_ / 128), 256, 0, stream>>>(qkv, wo, bo, out);
}